// Round 1
// baseline (167.479 us; speedup 1.0000x reference)
//
#include <hip/hip_runtime.h>
#include <math.h>

#define KE 14.3996f
#define R_MAX 6.0f

// ws layout (floats):
//  [0] ae  [1] 1/an  [2] pre = 0.5*KE*rs
//  [3..6]  coeffs (softplus)
//  [7..10] exps   (softplus)
//  [16..79] powtab[z] = z^ae  for z = 0..63
#define WS_POW 16

__device__ __forceinline__ float softplus_f(float x) {
    return log1pf(expf(x));
}

__global__ void zbl_prep(const float* __restrict__ a_exp,
                         const float* __restrict__ a_num,
                         const float* __restrict__ coefficients,
                         const float* __restrict__ exponents,
                         const float* __restrict__ rep_scale,
                         float* __restrict__ ws,
                         float* __restrict__ out) {
    int t = threadIdx.x;  // launched with 64 threads, 1 block
    float ae = softplus_f(a_exp[0]);
    if (t == 0) {
        ws[0] = ae;
        ws[1] = 1.0f / softplus_f(a_num[0]);
        ws[2] = 0.5f * KE * softplus_f(rep_scale[0]);
        out[0] = 0.0f;   // d_out is poisoned 0xAA before every timed call
    }
    if (t < 4) {
        ws[3 + t] = softplus_f(coefficients[t]);
        ws[7 + t] = softplus_f(exponents[t]);
    }
    // pow table: Z in [1,50)
    ws[WS_POW + t] = (t > 0) ? expf(ae * logf((float)t)) : 0.0f;
}

__global__ __launch_bounds__(256) void zbl_edges(
        const float* __restrict__ R,
        const int*   __restrict__ Z,
        const int*   __restrict__ idx_i,
        const int*   __restrict__ idx_j,
        const float* __restrict__ ws,
        float*       __restrict__ out,
        int nE) {
    __shared__ float spow[64];
    __shared__ float ssc[11];
    if (threadIdx.x < 64) spow[threadIdx.x] = ws[WS_POW + threadIdx.x];
    if (threadIdx.x < 11) ssc[threadIdx.x] = ws[threadIdx.x];
    __syncthreads();

    const float inv_an = ssc[1];
    const float c0 = ssc[3], c1 = ssc[4], c2 = ssc[5], c3 = ssc[6];
    const float e0 = ssc[7], e1 = ssc[8], e2 = ssc[9], e3 = ssc[10];
    const float kcut = (float)M_PI / R_MAX;   // pi/6

    float local = 0.0f;
    const int stride = gridDim.x * blockDim.x;
    for (int e = blockIdx.x * blockDim.x + threadIdx.x; e < nE; e += stride) {
        const int i = idx_i[e];
        const int j = idx_j[e];
        const float dx = R[3 * j + 0] - R[3 * i + 0];
        const float dy = R[3 * j + 1] - R[3 * i + 1];
        const float dz = R[3 * j + 2] - R[3 * i + 2];
        const float dr2 = dx * dx + dy * dy + dz * dz;
        // cutoff is exactly 0 at dr>=R_MAX; self-pairs masked out
        if ((i != j) && (dr2 < R_MAX * R_MAX)) {
            const float dr = fmaxf(sqrtf(dr2), 0.02f);
            const int zi_i = Z[i];
            const int zj_i = Z[j];
            const float zi = (float)zi_i;
            const float zj = (float)zj_i;
            const float pa = spow[zi_i] + spow[zj_i];     // Z_i^ae + Z_j^ae
            const float dist = dr * pa * inv_an;
            const float f = c0 * expf(-e0 * dist) + c1 * expf(-e1 * dist)
                          + c2 * expf(-e2 * dist) + c3 * expf(-e3 * dist);
            const float cut = 0.5f * (cosf(kcut * dr) + 1.0f);
            local += zi * zj / dr * f * cut;
        }
    }

    // 64-lane wave reduction
    for (int off = 32; off > 0; off >>= 1)
        local += __shfl_down(local, off);

    __shared__ float wsum[4];
    const int lane = threadIdx.x & 63;
    const int wave = threadIdx.x >> 6;
    if (lane == 0) wsum[wave] = local;
    __syncthreads();
    if (threadIdx.x == 0) {
        const float s = (wsum[0] + wsum[1] + wsum[2] + wsum[3]) * ssc[2];
        atomicAdd(out, s);
    }
}

extern "C" void kernel_launch(void* const* d_in, const int* in_sizes, int n_in,
                              void* d_out, int out_size, void* d_ws, size_t ws_size,
                              hipStream_t stream) {
    const float* R     = (const float*)d_in[0];
    const int*   Z     = (const int*)d_in[1];
    const int*   idx   = (const int*)d_in[2];
    const float* a_exp = (const float*)d_in[3];
    const float* a_num = (const float*)d_in[4];
    const float* coef  = (const float*)d_in[5];
    const float* expo  = (const float*)d_in[6];
    const float* rs    = (const float*)d_in[7];

    float* out = (float*)d_out;
    float* ws  = (float*)d_ws;

    const int nE = in_sizes[2] / 2;
    const int* idx_i = idx;
    const int* idx_j = idx + nE;

    zbl_prep<<<1, 64, 0, stream>>>(a_exp, a_num, coef, expo, rs, ws, out);

    const int block = 256;
    int grid = (nE + block - 1) / block;
    if (grid > 4096) grid = 4096;
    zbl_edges<<<grid, block, 0, stream>>>(R, Z, idx_i, idx_j, ws, out, nE);
}